// Round 1
// baseline (219.503 us; speedup 1.0000x reference)
//
#include <hip/hip_runtime.h>
#include <math.h>

#define NB 64
#define NN 1024
#define NC 128
#define NK 512

// Kernel 1: per-graph fp64 score computation + exact rank-sort top-k.
// Total order: score descending, index ascending (matches jax.lax.top_k
// stable tie-break). One block of 1024 threads per graph.
__global__ __launch_bounds__(1024) void score_rank_kernel(
    const float* __restrict__ x, const float* __restrict__ w,
    int* __restrict__ perm, float* __restrict__ gate)
{
    __shared__ double s_score[NN];
    __shared__ float s_w[NC];
    const int b = blockIdx.x;
    const int tid = threadIdx.x;
    if (tid < NC) s_w[tid] = w[tid];
    __syncthreads();

    // dot(x[b,tid,:], w) and ||w||^2, both in double
    double acc = 0.0, nw = 0.0;
    const float* xr = x + ((size_t)b * NN + tid) * NC;
    #pragma unroll 8
    for (int c = 0; c < NC; ++c) {
        double wc = (double)s_w[c];
        acc += (double)xr[c] * wc;
        nw  += wc * wc;
    }
    double s = tanh(acc / sqrt(nw));
    s_score[tid] = s;
    __syncthreads();

    // exact rank: number of elements strictly ahead of me in the total order
    const double my = s;
    int r = 0;
    for (int j = 0; j < NN; ++j) {
        double o = s_score[j];              // LDS broadcast (all lanes same addr)
        r += (o > my) || (o == my && j < tid);
    }
    if (r < NK) {
        perm[b * NK + r] = tid;
        gate[b * NK + r] = (float)my;
    }
}

// Kernel 2: x_pool[b,i,c] = x[b, perm[b,i], c] * gate[b,i]
__global__ void xpool_kernel(
    const float* __restrict__ x, const int* __restrict__ perm,
    const float* __restrict__ gate, float* __restrict__ out)
{
    int id = blockIdx.x * blockDim.x + threadIdx.x;   // < NB*NK*NC
    int c  = id & (NC - 1);
    int bi = id >> 7;            // b*NK + i
    int b  = bi >> 9;
    int pi = perm[bi];
    float g = gate[bi];
    out[id] = x[((size_t)b * NN + pi) * NC + c] * g;
}

// Kernel 3: adj_pooled[b,i,j] = ((adj[b,pi,pj]!=0) || (adj[b,pj,pi]!=0)) + (i==j)
// One block per output row (b,i); 256 threads cover j in 2 steps.
__global__ __launch_bounds__(256) void adjpool_kernel(
    const float* __restrict__ adj, const int* __restrict__ perm,
    float* __restrict__ out)
{
    const int row = blockIdx.x;        // b*NK + i
    const int b = row >> 9;
    const int i = row & (NK - 1);
    const int pi = perm[row];
    const float* ab = adj + (size_t)b * NN * NN;
    const int* pb = perm + b * NK;
    float* orow = out + (size_t)row * NK;

    for (int j = threadIdx.x; j < NK; j += blockDim.x) {
        int pj = pb[j];
        float v = ((ab[(size_t)pi * NN + pj] != 0.f) ||
                   (ab[(size_t)pj * NN + pi] != 0.f)) ? 1.f : 0.f;
        if (j == i) v += 1.f;
        orow[j] = v;
    }
}

extern "C" void kernel_launch(void* const* d_in, const int* in_sizes, int n_in,
                              void* d_out, int out_size, void* d_ws, size_t ws_size,
                              hipStream_t stream) {
    const float* x   = (const float*)d_in[0];
    const float* adj = (const float*)d_in[1];
    const float* w   = (const float*)d_in[2];
    float* out = (float*)d_out;

    // workspace: perm (NB*NK ints) then gate (NB*NK floats)
    int*   perm = (int*)d_ws;
    float* gate = (float*)((char*)d_ws + sizeof(int) * NB * NK);

    float* x_pool     = out;                              // NB*NK*NC
    float* adj_pooled = out + (size_t)NB * NK * NC;       // NB*NK*NK

    score_rank_kernel<<<NB, NN, 0, stream>>>(x, w, perm, gate);
    xpool_kernel<<<(NB * NK * NC) / 256, 256, 0, stream>>>(x, perm, gate, x_pool);
    adjpool_kernel<<<NB * NK, 256, 0, stream>>>(adj, perm, adj_pooled);
}

// Round 2
// 140.967 us; speedup vs baseline: 1.5571x; 1.5571x over previous
//
#include <hip/hip_runtime.h>
#include <math.h>

#define NB 64
#define NN 1024
#define NC 128
#define NK 512

// K1: per-graph fp64 score + exact rank-sort top-k. Also emits inverse perm.
__global__ __launch_bounds__(1024) void score_rank_kernel(
    const float* __restrict__ x, const float* __restrict__ w,
    int* __restrict__ perm, float* __restrict__ gate, int* __restrict__ inv)
{
    __shared__ double s_score[NN];
    __shared__ float s_w[NC];
    const int b = blockIdx.x;
    const int tid = threadIdx.x;
    if (tid < NC) s_w[tid] = w[tid];
    __syncthreads();

    double acc = 0.0, nw = 0.0;
    const float* xr = x + ((size_t)b * NN + tid) * NC;
    #pragma unroll 8
    for (int c = 0; c < NC; ++c) {
        double wc = (double)s_w[c];
        acc += (double)xr[c] * wc;
        nw  += wc * wc;
    }
    double s = tanh(acc / sqrt(nw));
    s_score[tid] = s;
    __syncthreads();

    const double my = s;
    int r = 0;
    for (int j = 0; j < NN; ++j) {
        double o = s_score[j];              // LDS broadcast
        r += (o > my) || (o == my && j < tid);
    }
    if (r < NK) {
        perm[b * NK + r] = tid;
        gate[b * NK + r] = (float)my;
    }
    inv[b * NN + tid] = (r < NK) ? r : -1;
}

// K2: x_pool[b,i,c] = x[b, perm[b,i], c] * gate[b,i]
__global__ void xpool_kernel(
    const float* __restrict__ x, const int* __restrict__ perm,
    const float* __restrict__ gate, float* __restrict__ out)
{
    int id = blockIdx.x * blockDim.x + threadIdx.x;   // < NB*NK*NC
    int c  = id & (NC - 1);
    int bi = id >> 7;            // b*NK + i
    int b  = bi >> 9;
    int pi = perm[bi];
    float g = gate[bi];
    out[id] = x[((size_t)b * NN + pi) * NC + c] * g;
}

// K3a: adj_pooled := eye  (float4 stores, 67 MB)
__global__ void adj_fill_kernel(float* __restrict__ out)
{
    size_t id = (size_t)blockIdx.x * blockDim.x + threadIdx.x;
    size_t base = id * 4;                  // first of 4 consecutive j
    int j4 = (int)(base & (NK - 1));
    size_t row = base >> 9;                // b*NK + i
    int i = (int)(row & (NK - 1));
    float4 v = make_float4(0.f, 0.f, 0.f, 0.f);
    if (i >= j4 && i < j4 + 4) ((float*)&v)[i - j4] = 1.0f;
    *(float4*)(out + base) = v;
}

// K3b: stream each selected row pi contiguously; for every nonzero column p
// that is itself selected (j = inv[p] >= 0), write 1.0 to (i,j) and (j,i)
// (2.0 on the diagonal). Covers R and R^T since all selected rows are scanned.
__global__ __launch_bounds__(256) void adj_scan_kernel(
    const float* __restrict__ adj, const int* __restrict__ perm,
    const int* __restrict__ inv, float* __restrict__ out)
{
    const int row = blockIdx.x;            // b*NK + i
    const int b = row >> 9;
    const int i = row & (NK - 1);
    const int pi = perm[row];
    const float4* arow = (const float4*)(adj + ((size_t)b * NN + pi) * NN);
    const int* invb = inv + b * NN;
    float* ob = out + (size_t)b * NK * NK;

    const int t = threadIdx.x;
    float4 v = arow[t];                    // 256 threads x float4 = 1024 cols
    #pragma unroll
    for (int u = 0; u < 4; ++u) {
        float e = ((const float*)&v)[u];
        if (e != 0.0f) {
            int p = t * 4 + u;
            int j = invb[p];               // L2-resident (256 KB total)
            if (j >= 0) {
                float val = (j == i) ? 2.0f : 1.0f;
                ob[(size_t)i * NK + j] = val;
                ob[(size_t)j * NK + i] = val;
            }
        }
    }
}

extern "C" void kernel_launch(void* const* d_in, const int* in_sizes, int n_in,
                              void* d_out, int out_size, void* d_ws, size_t ws_size,
                              hipStream_t stream) {
    const float* x   = (const float*)d_in[0];
    const float* adj = (const float*)d_in[1];
    const float* w   = (const float*)d_in[2];
    float* out = (float*)d_out;

    int*   perm = (int*)d_ws;                                    // NB*NK
    float* gate = (float*)((char*)d_ws + sizeof(int) * NB * NK); // NB*NK
    int*   inv  = (int*)((char*)d_ws + 2 * sizeof(int) * NB * NK); // NB*NN

    float* x_pool     = out;                              // NB*NK*NC
    float* adj_pooled = out + (size_t)NB * NK * NC;       // NB*NK*NK

    score_rank_kernel<<<NB, NN, 0, stream>>>(x, w, perm, gate, inv);
    xpool_kernel<<<(NB * NK * NC) / 256, 256, 0, stream>>>(x, perm, gate, x_pool);
    adj_fill_kernel<<<(NB * NK * NK / 4) / 256, 256, 0, stream>>>(adj_pooled);
    adj_scan_kernel<<<NB * NK, 256, 0, stream>>>(adj, perm, inv, adj_pooled);
}

// Round 3
// 136.197 us; speedup vs baseline: 1.6117x; 1.0350x over previous
//
#include <hip/hip_runtime.h>
#include <math.h>

#define NB 64
#define NN 1024
#define NC 128
#define NK 512

// K1: fp64 dot(x[row,:], w) — one wave per row, float2 per lane, tree reduce.
__global__ __launch_bounds__(256) void score_kernel(
    const float* __restrict__ x, const float* __restrict__ w,
    double* __restrict__ sacc)
{
    const int row  = blockIdx.x * 4 + (threadIdx.x >> 6);   // < NB*NN
    const int lane = threadIdx.x & 63;
    const float2 xv = *(const float2*)(x + (size_t)row * NC + lane * 2);
    const float2 wv = *(const float2*)(w + lane * 2);
    double acc = (double)xv.x * (double)wv.x + (double)xv.y * (double)wv.y;
    #pragma unroll
    for (int off = 32; off > 0; off >>= 1)
        acc += __shfl_xor(acc, off, 64);
    if (lane == 0) sacc[row] = acc;
}

// K2: exact rank-sort top-k on pre-tanh scores (monotone => same order).
// 4 blocks/graph x 256 threads; total order (score desc, idx asc).
__global__ __launch_bounds__(256) void rank_kernel(
    const double* __restrict__ sacc, const float* __restrict__ w,
    int* __restrict__ perm, float* __restrict__ gate, int* __restrict__ inv)
{
    __shared__ double s[NN];
    const int b = blockIdx.x >> 2;
    const int q = blockIdx.x & 3;
    const int t = threadIdx.x;
    for (int idx = t; idx < NN; idx += 256)
        s[idx] = sacc[(size_t)b * NN + idx];
    __syncthreads();

    const int n = q * 256 + t;
    const double my = s[n];
    int r = 0;
    for (int j = 0; j < NN; ++j) {
        double o = s[j];                       // LDS broadcast
        r += (o > my) || ((o == my) && (j < n));
    }
    inv[b * NN + n] = (r < NK) ? r : -1;
    if (r < NK) {
        double nw = 0.0;
        #pragma unroll 8
        for (int c = 0; c < NC; ++c) { double wc = (double)w[c]; nw += wc * wc; }
        perm[b * NK + r] = n;
        gate[b * NK + r] = (float)tanh(my / sqrt(nw));
    }
}

// K3: x_pool[b,i,c] = x[b,perm[b,i],c] * gate[b,i]  (float4)
__global__ void xpool_kernel(
    const float* __restrict__ x, const int* __restrict__ perm,
    const float* __restrict__ gate, float* __restrict__ out)
{
    int id = blockIdx.x * blockDim.x + threadIdx.x;   // < NB*NK*NC/4
    int c4 = id & (NC / 4 - 1);
    int bi = id >> 5;              // b*NK + i
    int b  = bi >> 9;
    int pi = perm[bi];
    float g = gate[bi];
    float4 v = *(const float4*)(x + ((size_t)b * NN + pi) * NC + c4 * 4);
    v.x *= g; v.y *= g; v.z *= g; v.w *= g;
    *(float4*)(out + (size_t)id * 4) = v;
}

// K4: stream selected rows of adj; set bits (i,j) and (j,i) in per-graph
// bitmap (16 u32 words per row of 512 bits). 16 blocks/graph x 32 rows.
__global__ __launch_bounds__(256) void adj_scan_kernel(
    const float* __restrict__ adj, const int* __restrict__ perm,
    const int* __restrict__ inv, unsigned* __restrict__ bm)
{
    const int b = blockIdx.x >> 4;
    const int chunk = blockIdx.x & 15;
    const int t = threadIdx.x;
    const int* invb = inv + b * NN;
    const float* ab = adj + (size_t)b * NN * NN;
    unsigned* bmb = bm + ((size_t)b * NK << 4);

    for (int rr = 0; rr < 32; ++rr) {
        int i = chunk * 32 + rr;
        int pi = perm[b * NK + i];
        float4 v = *(const float4*)(ab + (size_t)pi * NN + t * 4);
        #pragma unroll
        for (int u = 0; u < 4; ++u) {
            if (((const float*)&v)[u] != 0.0f) {
                int j = invb[t * 4 + u];
                if (j >= 0) {
                    atomicOr(bmb + (i << 4) + (j >> 5), 1u << (j & 31));
                    atomicOr(bmb + (j << 4) + (i >> 5), 1u << (i & 31));
                }
            }
        }
    }
}

// K5: adj_pooled[b,i,j] = bit(b,i,j) + (i==j), written once, float4 streams.
__global__ void adj_write_kernel(
    const unsigned* __restrict__ bm, float* __restrict__ out)
{
    int id = blockIdx.x * blockDim.x + threadIdx.x;   // < NB*NK*NK/4
    int j0  = (id & 127) * 4;      // 128 float4 per 512-row
    int row = id >> 7;             // b*NK + i
    int i   = row & (NK - 1);
    unsigned wv = bm[((size_t)row << 4) + (j0 >> 5)];
    int sh = j0 & 31;
    float4 v;
    float* vp = (float*)&v;
    #pragma unroll
    for (int u = 0; u < 4; ++u) {
        float e = (float)((wv >> (sh + u)) & 1u);
        if (i == j0 + u) e += 1.0f;
        vp[u] = e;
    }
    *(float4*)(out + (size_t)id * 4) = v;
}

extern "C" void kernel_launch(void* const* d_in, const int* in_sizes, int n_in,
                              void* d_out, int out_size, void* d_ws, size_t ws_size,
                              hipStream_t stream) {
    const float* x   = (const float*)d_in[0];
    const float* adj = (const float*)d_in[1];
    const float* w   = (const float*)d_in[2];
    float* out = (float*)d_out;

    // ws layout (8B-aligned first)
    char* p = (char*)d_ws;
    double*   sacc = (double*)p;                 p += sizeof(double) * NB * NN;   // 512 KB
    unsigned* bm   = (unsigned*)p;               p += sizeof(unsigned) * NB * NK * 16; // 2 MB
    int*      perm = (int*)p;                    p += sizeof(int) * NB * NK;      // 128 KB
    float*    gate = (float*)p;                  p += sizeof(float) * NB * NK;    // 128 KB
    int*      inv  = (int*)p;                                                      // 256 KB

    float* x_pool     = out;                           // NB*NK*NC
    float* adj_pooled = out + (size_t)NB * NK * NC;    // NB*NK*NK

    hipMemsetAsync(bm, 0, sizeof(unsigned) * NB * NK * 16, stream);
    score_kernel<<<NB * NN / 4, 256, 0, stream>>>(x, w, sacc);
    rank_kernel<<<NB * 4, 256, 0, stream>>>(sacc, w, perm, gate, inv);
    xpool_kernel<<<(NB * NK * NC / 4) / 256, 256, 0, stream>>>(x, perm, gate, x_pool);
    adj_scan_kernel<<<NB * 16, 256, 0, stream>>>(adj, perm, inv, bm);
    adj_write_kernel<<<(NB * NK * NK / 4) / 256, 256, 0, stream>>>(bm, adj_pooled);
}

// Round 4
// 98.752 us; speedup vs baseline: 2.2228x; 1.3792x over previous
//
#include <hip/hip_runtime.h>
#include <math.h>

#define NB 64
#define NN 1024
#define NC 128
#define NK 512

// K1: fp64 dot(x[row,:], w) — one wave per row, float2 per lane, tree reduce.
__global__ __launch_bounds__(256) void score_kernel(
    const float* __restrict__ x, const float* __restrict__ w,
    double* __restrict__ sacc)
{
    const int row  = blockIdx.x * 4 + (threadIdx.x >> 6);   // < NB*NN
    const int lane = threadIdx.x & 63;
    const float2 xv = *(const float2*)(x + (size_t)row * NC + lane * 2);
    const float2 wv = *(const float2*)(w + lane * 2);
    double acc = (double)xv.x * (double)wv.x + (double)xv.y * (double)wv.y;
    #pragma unroll
    for (int off = 32; off > 0; off >>= 1)
        acc += __shfl_xor(acc, off, 64);
    if (lane == 0) sacc[row] = acc;
}

// K2: exact rank-sort top-k on pre-tanh scores (monotone => same order as ref).
// 4 blocks/graph x 256 threads; total order (score desc, idx asc).
__global__ __launch_bounds__(256) void rank_kernel(
    const double* __restrict__ sacc, const float* __restrict__ w,
    int* __restrict__ perm, float* __restrict__ gate, int* __restrict__ inv)
{
    __shared__ double s[NN];
    __shared__ double s_rnw;     // 1/sqrt(||w||^2)
    const int b = blockIdx.x >> 2;
    const int q = blockIdx.x & 3;
    const int t = threadIdx.x;
    for (int idx = t; idx < NN; idx += 256)
        s[idx] = sacc[(size_t)b * NN + idx];
    if (t < 64) {                 // wave 0: ||w||^2 via shuffle
        double p = (double)w[t] * (double)w[t]
                 + (double)w[t + 64] * (double)w[t + 64];
        #pragma unroll
        for (int off = 32; off > 0; off >>= 1)
            p += __shfl_xor(p, off, 64);
        if (t == 0) s_rnw = 1.0 / sqrt(p);
    }
    __syncthreads();

    const int n = q * 256 + t;
    const double my = s[n];
    int r = 0;
    #pragma unroll 8
    for (int j = 0; j < NN; ++j) {
        double o = s[j];                       // LDS broadcast
        r += (o > my) || ((o == my) && (j < n));
    }
    inv[b * NN + n] = (r < NK) ? r : -1;
    if (r < NK) {
        perm[b * NK + r] = n;
        gate[b * NK + r] = (float)tanh(my * s_rnw);
    }
}

// K3: x_pool[b,i,c] = x[b,perm[b,i],c] * gate[b,i]  (float4)
__global__ void xpool_kernel(
    const float* __restrict__ x, const int* __restrict__ perm,
    const float* __restrict__ gate, float* __restrict__ out)
{
    int id = blockIdx.x * blockDim.x + threadIdx.x;   // < NB*NK*NC/4
    int c4 = id & (NC / 4 - 1);
    int bi = id >> 5;              // b*NK + i
    int b  = bi >> 9;
    int pi = perm[bi];
    float g = gate[bi];
    float4 v = *(const float4*)(x + ((size_t)b * NN + pi) * NC + c4 * 4);
    v.x *= g; v.y *= g; v.z *= g; v.w *= g;
    *(float4*)(out + (size_t)id * 4) = v;
}

// K4: 4 blocks/graph; each builds a partial 512x512 bitmap in LDS (32 KB)
// from 128 selected rows, with next-row prefetch; LDS atomicOr only.
// Partial bitmaps dumped coalesced to pb[graph][chunk][NK][16].
__global__ __launch_bounds__(1024) void adj_scan_kernel(
    const float* __restrict__ adj, const int* __restrict__ perm,
    const int* __restrict__ inv, unsigned* __restrict__ pb)
{
    __shared__ unsigned bits[NK * 16];   // 32 KB
    __shared__ int sinv[NN];             // 4 KB
    const int b = blockIdx.x >> 2;
    const int chunk = blockIdx.x & 3;    // which 128 pooled rows
    const int t = threadIdx.x;
    for (int idx = t; idx < NK * 16; idx += 1024) bits[idx] = 0;
    for (int idx = t; idx < NN; idx += 1024) sinv[idx] = inv[b * NN + idx];
    __syncthreads();

    const float* ab = adj + (size_t)b * NN * NN;
    const int* permb = perm + b * NK;
    const int g  = t >> 8;               // row-group 0..3
    const int lt = t & 255;              // lane within group

    int i = chunk * 128 + g;             // pooled row index, stride 4
    int pi = permb[i];
    float4 v = *(const float4*)(ab + (size_t)pi * NN + lt * 4);
    for (int it = 0; it < 32; ++it) {
        int inext = i + 4;
        int pin = 0; float4 vn = v;
        if (it < 31) {                   // prefetch next row before processing
            pin = permb[inext];
            vn = *(const float4*)(ab + (size_t)pin * NN + lt * 4);
        }
        #pragma unroll
        for (int u = 0; u < 4; ++u) {
            if (((const float*)&v)[u] != 0.0f) {
                int j = sinv[lt * 4 + u];
                if (j >= 0) {
                    atomicOr(&bits[(i << 4) + (j >> 5)], 1u << (j & 31));
                    atomicOr(&bits[(j << 4) + (i >> 5)], 1u << (i & 31));
                }
            }
        }
        i = inext; pi = pin; v = vn;
    }
    __syncthreads();
    unsigned* outp = pb + (size_t)(b * 4 + chunk) * NK * 16;
    for (int idx = t; idx < NK * 16; idx += 1024) outp[idx] = bits[idx];
}

// K5: adj_pooled[b,i,j] = (OR of 4 partial bits) + (i==j), float4 streams.
__global__ void adj_write_kernel(
    const unsigned* __restrict__ pb, float* __restrict__ out)
{
    int id = blockIdx.x * blockDim.x + threadIdx.x;   // < NB*NK*NK/4
    int j0  = (id & 127) * 4;      // 128 float4 per 512-row
    int row = id >> 7;             // b*NK + i
    int i   = row & (NK - 1);
    int bg  = row >> 9;
    int wi  = j0 >> 5;
    const unsigned* base = pb + ((size_t)bg * 4 * NK + i) * 16 + wi;
    unsigned m = base[0] | base[NK * 16] | base[2 * NK * 16] | base[3 * NK * 16];
    int sh = j0 & 31;
    float4 v;
    float* vp = (float*)&v;
    #pragma unroll
    for (int u = 0; u < 4; ++u) {
        float e = (float)((m >> (sh + u)) & 1u);
        if (i == j0 + u) e += 1.0f;
        vp[u] = e;
    }
    *(float4*)(out + (size_t)id * 4) = v;
}

extern "C" void kernel_launch(void* const* d_in, const int* in_sizes, int n_in,
                              void* d_out, int out_size, void* d_ws, size_t ws_size,
                              hipStream_t stream) {
    const float* x   = (const float*)d_in[0];
    const float* adj = (const float*)d_in[1];
    const float* w   = (const float*)d_in[2];
    float* out = (float*)d_out;

    // ws layout (8B-aligned first)
    char* p = (char*)d_ws;
    double*   sacc = (double*)p;    p += sizeof(double) * NB * NN;            // 512 KB
    unsigned* pb   = (unsigned*)p;  p += sizeof(unsigned) * NB * 4 * NK * 16; // 8 MB
    int*      perm = (int*)p;       p += sizeof(int) * NB * NK;               // 128 KB
    float*    gate = (float*)p;     p += sizeof(float) * NB * NK;             // 128 KB
    int*      inv  = (int*)p;                                                 // 256 KB

    float* x_pool     = out;                           // NB*NK*NC
    float* adj_pooled = out + (size_t)NB * NK * NC;    // NB*NK*NK

    score_kernel<<<NB * NN / 4, 256, 0, stream>>>(x, w, sacc);
    rank_kernel<<<NB * 4, 256, 0, stream>>>(sacc, w, perm, gate, inv);
    xpool_kernel<<<(NB * NK * NC / 4) / 256, 256, 0, stream>>>(x, perm, gate, x_pool);
    adj_scan_kernel<<<NB * 4, 1024, 0, stream>>>(adj, perm, inv, pb);
    adj_write_kernel<<<(NB * NK * NK / 4) / 256, 256, 0, stream>>>(pb, adj_pooled);
}